// Round 2
// baseline (17125.169 us; speedup 1.0000x reference)
//
#include <hip/hip_runtime.h>
#include <cmath>

#define BB 64
#define TT 250
#define CC 1024
#define UU 512
#define GG 1536   // 3U
#define NB 256    // scan grid: 1 block/CU, exactly co-resident (LDS-limited to 1/CU)

// workspace layout (float offsets)
#define O_XGF 0
#define O_XGB 24576000      // T*B*G = 250*64*1536
#define O_UT  49152000      // 2*512*3*512
#define O_HT  50724864      // 2 bufs * 2 dirs * 512*64
#define O_MF  50855936      // T*B
#define O_BAR 50871936      // 256 uint step-barrier counters
// total ~50,872,192 floats = ~203.5 MB

__global__ __launch_bounds__(256) void prep_kernel(
    const unsigned char* __restrict__ mraw,
    float* __restrict__ ut, float* __restrict__ mf, float* __restrict__ ht,
    unsigned int* __restrict__ bar,
    const float* __restrict__ Uf, const float* __restrict__ Ub)
{
  int idx = blockIdx.x * 256 + threadIdx.x;
  // transpose U into ut[(d*512+u)*1536 + g*512 + k] = U_d[k][g*512+u]
  if (idx < 2*512*3*512) {
    int k = idx & 511;
    int r = idx >> 9;
    int g = r % 3;
    int rest = r / 3;        // d*512 + u
    int u = rest & 511;
    int dd = rest >> 9;
    const float* Um = dd ? Ub : Uf;
    ut[idx] = Um[k*GG + (g << 9) + u];
  }
  if (idx < 131072) ht[idx] = 0.0f;      // zero both h ping-pong buffers
  if (idx < 256) bar[idx] = 0u;          // zero barrier counters (every call: replays!)
  // mask -> float [t][b]; detect bool8 vs int32 storage via byte 1 (mask[0][1] true)
  if (idx < BB*TT) {
    int b = idx / TT, t = idx - b*TT;
    bool bytefmt = (mraw[1] == 1);
    bool mv = bytefmt ? (mraw[idx] != 0) : (((const int*)mraw)[idx] != 0);
    mf[t*BB + b] = mv ? 1.0f : 0.0f;
  }
}

// C = A(16000x1024) * W(1024x1536) + bias, both directions; out XG[t][b][g].
__global__ __launch_bounds__(256) void gemm_xg(
    const float* __restrict__ A,
    const float* __restrict__ Wf, const float* __restrict__ Wb,
    const float* __restrict__ bf, const float* __restrict__ bb,
    float* __restrict__ xgf, float* __restrict__ xgb)
{
  __shared__ float As[16][132];
  __shared__ float Bs[16][128];
  const int tid = threadIdx.x;
  const int m0 = blockIdx.x * 128;
  const int n0 = blockIdx.y * 128;
  const int d  = (n0 >= GG) ? 1 : 0;
  const int nl0 = n0 - d*GG;
  const float* Wm  = d ? Wb : Wf;
  const float* bias = d ? bb : bf;
  float* xg = d ? xgb : xgf;
  const int tm = (tid >> 4) << 3;
  const int tn = (tid & 15) << 3;
  float acc[8][8];
  #pragma unroll
  for (int i = 0; i < 8; i++)
    #pragma unroll
    for (int j = 0; j < 8; j++) acc[i][j] = 0.0f;
  for (int k0 = 0; k0 < CC; k0 += 16) {
    #pragma unroll
    for (int j = 0; j < 2; j++) {
      int f = tid*2 + j;
      int r = f >> 2;
      int kk = (f & 3) << 2;
      float4 av = *(const float4*)(A + (size_t)(m0+r)*CC + k0 + kk);
      As[kk+0][r] = av.x; As[kk+1][r] = av.y; As[kk+2][r] = av.z; As[kk+3][r] = av.w;
    }
    #pragma unroll
    for (int j = 0; j < 2; j++) {
      int f = tid*2 + j;
      int kr = f >> 5;
      int nn = (f & 31) << 2;
      *(float4*)&Bs[kr][nn] = *(const float4*)(Wm + (size_t)(k0+kr)*GG + nl0 + nn);
    }
    __syncthreads();
    #pragma unroll
    for (int k = 0; k < 16; k++) {
      float4 a0 = *(const float4*)&As[k][tm];
      float4 a1 = *(const float4*)&As[k][tm+4];
      float4 b0 = *(const float4*)&Bs[k][tn];
      float4 b1 = *(const float4*)&Bs[k][tn+4];
      float av[8] = {a0.x,a0.y,a0.z,a0.w,a1.x,a1.y,a1.z,a1.w};
      float bv[8] = {b0.x,b0.y,b0.z,b0.w,b1.x,b1.y,b1.z,b1.w};
      #pragma unroll
      for (int i = 0; i < 8; i++)
        #pragma unroll
        for (int jj = 0; jj < 8; jj++) acc[i][jj] = fmaf(av[i], bv[jj], acc[i][jj]);
    }
    __syncthreads();
  }
  float bv8[8];
  #pragma unroll
  for (int j = 0; j < 8; j++) bv8[j] = bias[nl0 + tn + j];
  #pragma unroll
  for (int i = 0; i < 8; i++) {
    int m = m0 + tm + i;
    int b = m / TT;
    int t = m - b*TT;
    float* o = xg + (size_t)(t*BB + b)*GG + nl0 + tn;
    float4 o0 = {acc[i][0]+bv8[0], acc[i][1]+bv8[1], acc[i][2]+bv8[2], acc[i][3]+bv8[3]};
    float4 o1 = {acc[i][4]+bv8[4], acc[i][5]+bv8[5], acc[i][6]+bv8[6], acc[i][7]+bv8[7]};
    *(float4*)o = o0; *(float4*)(o+4) = o1;
  }
}

// Persistent scan: all 250 steps in ONE kernel. 256 blocks (d = bid>>7,
// utile = bid&127), 4 waves/block, wave = one u, lane = batch row b.
// h_prev for the gate blend lives in a register (thread's own prior output);
// global h ping-pong buffers only broadcast h for the matvec.
__global__ __launch_bounds__(256, 1) void gru_scan(
    const float* __restrict__ xgf, const float* __restrict__ xgb,
    const float* __restrict__ ut, const float* __restrict__ bf,
    const float* __restrict__ bb, const float* __restrict__ mf,
    float* __restrict__ ht, unsigned int* __restrict__ bar,
    float* __restrict__ out)
{
  extern __shared__ float hbuf[];          // [512][64] = 128 KB (dynamic LDS)
  const int tid  = threadIdx.x;
  const int lane = tid & 63;               // batch index b
  const int d    = blockIdx.x >> 7;
  int u_ = ((blockIdx.x & 127) << 2) | (tid >> 6);
  const int u = __builtin_amdgcn_readfirstlane(u_);   // wave-uniform -> s_load addressing
  const float* xgd  = d ? xgb : xgf;
  const float* bias = (d ? bb : bf) + GG;  // recurrent bias row b[1]
  const float b1z = bias[u], b1r = bias[512+u], b1h = bias[1024+u];
  const float* uz = ut + (size_t)((d << 9) | u) * GG;
  const float* ur = uz + 512;
  const float* uh = ur + 512;
  float hprev = 0.0f;

  for (int s = 0; s < TT; s++) {
    if (s) {
      // device barrier: release prior-step h stores, arrive, spin, acquire
      __threadfence();
      __syncthreads();
      if (tid == 0) {
        __hip_atomic_fetch_add(&bar[s], 1u, __ATOMIC_RELEASE, __HIP_MEMORY_SCOPE_AGENT);
        while (__hip_atomic_load(&bar[s], __ATOMIC_ACQUIRE, __HIP_MEMORY_SCOPE_AGENT) < NB)
          __builtin_amdgcn_s_sleep(2);
      }
      __syncthreads();
    }
    const int t = d ? (TT-1-s) : s;
    // xg + mask loads first: uncoalesced (3 lines/lane), latency hides under staging
    const float* xgp = xgd + (size_t)(t*BB + lane)*GG;
    float xz = xgp[u];
    float xr = xgp[512 + u];
    float xh = xgp[1024 + u];
    float m  = mf[t*BB + lane];
    // stage h[512][64] global -> LDS, coalesced float4
    const float4* src = (const float4*)(ht + (((s & 1) << 1 | d) << 15));
    float4* dst = (float4*)hbuf;
    #pragma unroll
    for (int j = 0; j < 32; j++) dst[j*256 + tid] = src[j*256 + tid];
    __syncthreads();
    // 3 dot products over k: conflict-free ds_read (2 lanes/bank) + scalar-loaded U
    float az = 0.0f, ar = 0.0f, ah = 0.0f;
    #pragma unroll 32
    for (int k = 0; k < 512; k++) {
      float hk = hbuf[(k << 6) | lane];
      az = fmaf(hk, uz[k], az);
      ar = fmaf(hk, ur[k], ar);
      ah = fmaf(hk, uh[k], ah);
    }
    // gates
    float z  = 1.0f / (1.0f + expf(-(xz + az + b1z)));
    float r  = 1.0f / (1.0f + expf(-(xr + ar + b1r)));
    float cc = tanhf(xh + r * (ah + b1h));
    float hn = z*hprev + (1.0f - z)*cc;
    hn = (m != 0.0f) ? hn : hprev;
    hprev = hn;
    float* hout = ht + ((((s & 1) ^ 1) << 1 | d) << 15);
    hout[(u << 6) | lane] = hn;
    out[(size_t)(lane*TT + t)*1024 + (d << 9) + u] = hn;
    if (s == TT-1)
      out[(size_t)16384000 + (lane << 10) + (d << 9) + u] = hn;
  }
}

extern "C" void kernel_launch(void* const* d_in, const int* in_sizes, int n_in,
                              void* d_out, int out_size, void* d_ws, size_t ws_size,
                              hipStream_t stream) {
  const float* X  = (const float*)d_in[0];
  const unsigned char* Mk = (const unsigned char*)d_in[1];
  const float* Wf = (const float*)d_in[2];
  const float* Uf = (const float*)d_in[3];
  const float* bf = (const float*)d_in[4];
  const float* Wb = (const float*)d_in[5];
  const float* Ub = (const float*)d_in[6];
  const float* bb = (const float*)d_in[7];
  float* out = (float*)d_out;
  float* ws  = (float*)d_ws;
  float* xgf = ws + O_XGF;
  float* xgb = ws + O_XGB;
  float* ut  = ws + O_UT;
  float* ht  = ws + O_HT;
  float* mf  = ws + O_MF;
  unsigned int* bar = (unsigned int*)(ws + O_BAR);

  static int attr_done = 0;   // host-side only; idempotent, no effect on device work
  hipFuncSetAttribute((const void*)gru_scan,
                      hipFuncAttributeMaxDynamicSharedMemorySize, 131072);

  prep_kernel<<<dim3(6144), dim3(256), 0, stream>>>(Mk, ut, mf, ht, bar, Uf, Ub);
  gemm_xg<<<dim3(125, 24), dim3(256), 0, stream>>>(X, Wf, Wb, bf, bb, xgf, xgb);
  gru_scan<<<dim3(NB), dim3(256), 131072, stream>>>(xgf, xgb, ut, bf, bb, mf, ht, bar, out);
}

// Round 3
// 9170.509 us; speedup vs baseline: 1.8674x; 1.8674x over previous
//
#include <hip/hip_runtime.h>
#include <cmath>

#define BB 64
#define TT 250
#define CC 1024
#define UU 512
#define GG 1536   // 3U
#define NB 256    // scan grid: 1 block/CU, exactly co-resident (LDS-limited to 1/CU)

// workspace layout (float offsets)
#define O_XGF 0
#define O_XGB 24576000      // T*B*G = 250*64*1536
#define O_UT  49152000      // 2*512*3*512
#define O_HT  50724864      // 2 bufs * 2 dirs * 512*64
#define O_MF  50855936      // T*B
#define O_BAR 50871936      // 256 uint per-block arrival slots (distributed barrier)
// total ~50,872,192 floats = ~203.5 MB

__global__ __launch_bounds__(256) void prep_kernel(
    const unsigned char* __restrict__ mraw,
    float* __restrict__ ut, float* __restrict__ mf, float* __restrict__ ht,
    unsigned int* __restrict__ bar,
    const float* __restrict__ Uf, const float* __restrict__ Ub)
{
  int idx = blockIdx.x * 256 + threadIdx.x;
  // transpose U into ut[(d*512+u)*1536 + g*512 + k] = U_d[k][g*512+u]
  if (idx < 2*512*3*512) {
    int k = idx & 511;
    int r = idx >> 9;
    int g = r % 3;
    int rest = r / 3;        // d*512 + u
    int u = rest & 511;
    int dd = rest >> 9;
    const float* Um = dd ? Ub : Uf;
    ut[idx] = Um[k*GG + (g << 9) + u];
  }
  if (idx < 131072) ht[idx] = 0.0f;      // zero both h ping-pong buffers
  if (idx < 256) bar[idx] = 0u;          // zero arrival slots (every call: replays!)
  // mask -> float [t][b]; detect bool8 vs int32 storage via byte 1 (mask[0][1] true)
  if (idx < BB*TT) {
    int b = idx / TT, t = idx - b*TT;
    bool bytefmt = (mraw[1] == 1);
    bool mv = bytefmt ? (mraw[idx] != 0) : (((const int*)mraw)[idx] != 0);
    mf[t*BB + b] = mv ? 1.0f : 0.0f;
  }
}

// C = A(16000x1024) * W(1024x1536) + bias, both directions; out XG[t][b][g].
__global__ __launch_bounds__(256) void gemm_xg(
    const float* __restrict__ A,
    const float* __restrict__ Wf, const float* __restrict__ Wb,
    const float* __restrict__ bf, const float* __restrict__ bb,
    float* __restrict__ xgf, float* __restrict__ xgb)
{
  __shared__ float As[16][132];
  __shared__ float Bs[16][128];
  const int tid = threadIdx.x;
  const int m0 = blockIdx.x * 128;
  const int n0 = blockIdx.y * 128;
  const int d  = (n0 >= GG) ? 1 : 0;
  const int nl0 = n0 - d*GG;
  const float* Wm  = d ? Wb : Wf;
  const float* bias = d ? bb : bf;
  float* xg = d ? xgb : xgf;
  const int tm = (tid >> 4) << 3;
  const int tn = (tid & 15) << 3;
  float acc[8][8];
  #pragma unroll
  for (int i = 0; i < 8; i++)
    #pragma unroll
    for (int j = 0; j < 8; j++) acc[i][j] = 0.0f;
  for (int k0 = 0; k0 < CC; k0 += 16) {
    #pragma unroll
    for (int j = 0; j < 2; j++) {
      int f = tid*2 + j;
      int r = f >> 2;
      int kk = (f & 3) << 2;
      float4 av = *(const float4*)(A + (size_t)(m0+r)*CC + k0 + kk);
      As[kk+0][r] = av.x; As[kk+1][r] = av.y; As[kk+2][r] = av.z; As[kk+3][r] = av.w;
    }
    #pragma unroll
    for (int j = 0; j < 2; j++) {
      int f = tid*2 + j;
      int kr = f >> 5;
      int nn = (f & 31) << 2;
      *(float4*)&Bs[kr][nn] = *(const float4*)(Wm + (size_t)(k0+kr)*GG + nl0 + nn);
    }
    __syncthreads();
    #pragma unroll
    for (int k = 0; k < 16; k++) {
      float4 a0 = *(const float4*)&As[k][tm];
      float4 a1 = *(const float4*)&As[k][tm+4];
      float4 b0 = *(const float4*)&Bs[k][tn];
      float4 b1 = *(const float4*)&Bs[k][tn+4];
      float av[8] = {a0.x,a0.y,a0.z,a0.w,a1.x,a1.y,a1.z,a1.w};
      float bv[8] = {b0.x,b0.y,b0.z,b0.w,b1.x,b1.y,b1.z,b1.w};
      #pragma unroll
      for (int i = 0; i < 8; i++)
        #pragma unroll
        for (int jj = 0; jj < 8; jj++) acc[i][jj] = fmaf(av[i], bv[jj], acc[i][jj]);
    }
    __syncthreads();
  }
  float bv8[8];
  #pragma unroll
  for (int j = 0; j < 8; j++) bv8[j] = bias[nl0 + tn + j];
  #pragma unroll
  for (int i = 0; i < 8; i++) {
    int m = m0 + tm + i;
    int b = m / TT;
    int t = m - b*TT;
    float* o = xg + (size_t)(t*BB + b)*GG + nl0 + tn;
    float4 o0 = {acc[i][0]+bv8[0], acc[i][1]+bv8[1], acc[i][2]+bv8[2], acc[i][3]+bv8[3]};
    float4 o1 = {acc[i][4]+bv8[4], acc[i][5]+bv8[5], acc[i][6]+bv8[6], acc[i][7]+bv8[7]};
    *(float4*)o = o0; *(float4*)(o+4) = o1;
  }
}

// Persistent scan: all 250 steps in ONE kernel. 256 blocks (d = bid>>7,
// utile = bid&127), 4 waves/block, wave = one u, lane = batch row b.
// Device barrier = distributed slots: each block release-stores its step to
// bar[bid] (no RMW contention), wave 0 polls all 256 slots, acquire fence.
__global__ __launch_bounds__(256, 1) void gru_scan(
    const float* __restrict__ xgf, const float* __restrict__ xgb,
    const float* __restrict__ ut, const float* __restrict__ bf,
    const float* __restrict__ bb, const float* __restrict__ mf,
    float* __restrict__ ht, unsigned int* __restrict__ bar,
    float* __restrict__ out)
{
  extern __shared__ float hbuf[];          // [512][64] = 128 KB (dynamic LDS)
  const int tid  = threadIdx.x;
  const int lane = tid & 63;               // batch index b
  const int bid  = blockIdx.x;
  const int d    = bid >> 7;
  int u_ = ((bid & 127) << 2) | (tid >> 6);
  const int u = __builtin_amdgcn_readfirstlane(u_);   // wave-uniform -> s_load addressing
  const float* xgd  = d ? xgb : xgf;
  const float* bias = (d ? bb : bf) + GG;  // recurrent bias row b[1]
  const float b1z = bias[u], b1r = bias[512+u], b1h = bias[1024+u];
  const float* uz = ut + (size_t)((d << 9) | u) * GG;
  const float* ur = uz + 512;
  const float* uh = ur + 512;
  float hprev = 0.0f;

  for (int s = 0; s < TT; s++) {
    const int t = d ? (TT-1-s) : s;
    // xg + mask loads BEFORE the barrier: HBM latency hides under the spin
    const float* xgp = xgd + (size_t)(t*BB + lane)*GG;
    float xz = xgp[u];
    float xr = xgp[512 + u];
    float xh = xgp[1024 + u];
    float m  = mf[t*BB + lane];
    if (s) {
      __syncthreads();   // all waves done with step s-1 (h stores issued, hbuf free)
      if (tid == 0)
        __hip_atomic_store(&bar[bid], (unsigned)s, __ATOMIC_RELEASE, __HIP_MEMORY_SCOPE_AGENT);
      if (tid < 64) {    // wave 0 polls: 4 slots/lane, relaxed device-scope loads
        const int i0 = tid << 2;
        while (true) {
          unsigned v0 = __hip_atomic_load(&bar[i0+0], __ATOMIC_RELAXED, __HIP_MEMORY_SCOPE_AGENT);
          unsigned v1 = __hip_atomic_load(&bar[i0+1], __ATOMIC_RELAXED, __HIP_MEMORY_SCOPE_AGENT);
          unsigned v2 = __hip_atomic_load(&bar[i0+2], __ATOMIC_RELAXED, __HIP_MEMORY_SCOPE_AGENT);
          unsigned v3 = __hip_atomic_load(&bar[i0+3], __ATOMIC_RELAXED, __HIP_MEMORY_SCOPE_AGENT);
          int ok = (v0 >= (unsigned)s) && (v1 >= (unsigned)s) &&
                   (v2 >= (unsigned)s) && (v3 >= (unsigned)s);
          if (__all(ok)) break;
          __builtin_amdgcn_s_sleep(1);
        }
      }
      __syncthreads();
      __builtin_amdgcn_fence(__ATOMIC_ACQUIRE, "agent");  // invalidate stale L1/L2
    }
    // stage h[512][64] global -> LDS, coalesced float4
    const float4* src = (const float4*)(ht + (((s & 1) << 1 | d) << 15));
    float4* dst = (float4*)hbuf;
    #pragma unroll
    for (int j = 0; j < 32; j++) dst[j*256 + tid] = src[j*256 + tid];
    __syncthreads();
    // 3 dot products over k: conflict-free ds_read (2 lanes/bank) + scalar-loaded U
    float az = 0.0f, ar = 0.0f, ah = 0.0f;
    #pragma unroll 32
    for (int k = 0; k < 512; k++) {
      float hk = hbuf[(k << 6) | lane];
      az = fmaf(hk, uz[k], az);
      ar = fmaf(hk, ur[k], ar);
      ah = fmaf(hk, uh[k], ah);
    }
    // gates
    float z  = 1.0f / (1.0f + expf(-(xz + az + b1z)));
    float r  = 1.0f / (1.0f + expf(-(xr + ar + b1r)));
    float cc = tanhf(xh + r * (ah + b1h));
    float hn = z*hprev + (1.0f - z)*cc;
    hn = (m != 0.0f) ? hn : hprev;
    hprev = hn;
    float* hout = ht + ((((s & 1) ^ 1) << 1 | d) << 15);
    hout[(u << 6) | lane] = hn;
    out[(size_t)(lane*TT + t)*1024 + (d << 9) + u] = hn;
    if (s == TT-1)
      out[16384000ull + ((size_t)lane << 10) + (d << 9) + u] = hn;
  }
}

extern "C" void kernel_launch(void* const* d_in, const int* in_sizes, int n_in,
                              void* d_out, int out_size, void* d_ws, size_t ws_size,
                              hipStream_t stream) {
  const float* X  = (const float*)d_in[0];
  const unsigned char* Mk = (const unsigned char*)d_in[1];
  const float* Wf = (const float*)d_in[2];
  const float* Uf = (const float*)d_in[3];
  const float* bf = (const float*)d_in[4];
  const float* Wb = (const float*)d_in[5];
  const float* Ub = (const float*)d_in[6];
  const float* bb = (const float*)d_in[7];
  float* out = (float*)d_out;
  float* ws  = (float*)d_ws;
  float* xgf = ws + O_XGF;
  float* xgb = ws + O_XGB;
  float* ut  = ws + O_UT;
  float* ht  = ws + O_HT;
  float* mf  = ws + O_MF;
  unsigned int* bar = (unsigned int*)(ws + O_BAR);

  hipFuncSetAttribute((const void*)gru_scan,
                      hipFuncAttributeMaxDynamicSharedMemorySize, 131072);

  prep_kernel<<<dim3(6144), dim3(256), 0, stream>>>(Mk, ut, mf, ht, bar, Uf, Ub);
  gemm_xg<<<dim3(125, 24), dim3(256), 0, stream>>>(X, Wf, Wb, bf, bb, xgf, xgb);
  gru_scan<<<dim3(NB), dim3(256), 131072, stream>>>(xgf, xgb, ut, bf, bb, mf, ht, bar, out);
}